// Round 1
// 1125.365 us; speedup vs baseline: 1.0374x; 1.0374x over previous
//
#include <hip/hip_runtime.h>
#include <hip/hip_bf16.h>

#define AS1 __attribute__((address_space(1)))
#define AS3 __attribute__((address_space(3)))

typedef __attribute__((ext_vector_type(4))) float  f32x4;
typedef __attribute__((ext_vector_type(8))) __bf16 bf16x8;
typedef __attribute__((ext_vector_type(2))) __bf16 bf16x2;
typedef __attribute__((ext_vector_type(4))) unsigned int uint4_;

static __device__ __forceinline__ unsigned short f2bf_rne(float f) {
    unsigned int u = __builtin_bit_cast(unsigned int, f);
    u += 0x7fffu + ((u >> 16) & 1u);
    return (unsigned short)(u >> 16);
}

static __device__ __forceinline__ unsigned int pack2(float a, float b) {
#if __has_builtin(__builtin_amdgcn_cvt_pk_bf16_f32)
    bf16x2 r = __builtin_amdgcn_cvt_pk_bf16_f32(a, b);
    return __builtin_bit_cast(unsigned int, r);
#else
    return (unsigned int)f2bf_rne(a) | ((unsigned int)f2bf_rne(b) << 16);
#endif
}

// ---------------------------------------------------------------------------
// K0a: convert w_e = attn_w[:, 1024:3072] (1024 x 2048) fp32 -> bf16 bits
// ---------------------------------------------------------------------------
__global__ __launch_bounds__(256) void convwe_kernel(
    const float* __restrict__ attn_w, unsigned short* __restrict__ Bw)
{
    const int idx = (blockIdx.x * 256 + threadIdx.x) * 8;  // < 1024*2048
    const int h = idx >> 11;
    const int e = idx & 2047;
    const float* src = attn_w + h * 3072 + 1024 + e;
    f32x4 v0 = *(const f32x4*)src;
    f32x4 v1 = *(const f32x4*)(src + 4);
    uint4_ o;
    o.x = pack2(v0.x, v0.y); o.y = pack2(v0.z, v0.w);
    o.z = pack2(v1.x, v1.y); o.w = pack2(v1.z, v1.w);
    *(uint4_*)(Bw + idx) = o;
}

// ---------------------------------------------------------------------------
// K0c: convert enc (65536 x 2048) fp32 -> bf16 bits. Grid-stride (G11):
// 2048 blocks x 32 iters amortizes per-block setup vs 65536 tiny blocks.
// ---------------------------------------------------------------------------
__global__ __launch_bounds__(256) void convenc_kernel(
    const float* __restrict__ enc, unsigned short* __restrict__ dst)
{
    size_t idx = ((size_t)blockIdx.x * 256 + threadIdx.x) * 8;
    const size_t step = (size_t)2048 * 256 * 8;
#pragma unroll 4
    for (int i = 0; i < 32; ++i) {
        f32x4 v0 = *(const f32x4*)(enc + idx);
        f32x4 v1 = *(const f32x4*)(enc + idx + 4);
        uint4_ o;
        o.x = pack2(v0.x, v0.y); o.y = pack2(v0.z, v0.w);
        o.z = pack2(v1.x, v1.y); o.w = pack2(v1.z, v1.w);
        *(uint4_*)(dst + idx) = o;
        idx += step;
    }
}

// ---------------------------------------------------------------------------
// K0b: hid_proj[b,h] = sum_k hidden[b,k] * attn_w[h,k] + attn_b[h]   (fp32)
// ---------------------------------------------------------------------------
__global__ __launch_bounds__(256) void hidproj_kernel(
    const float* __restrict__ hidden, const float* __restrict__ attn_w,
    const float* __restrict__ attn_b, float* __restrict__ hp)
{
    __shared__ float wrow[1024];
    const int h = blockIdx.x;
    const int t = threadIdx.x;
#pragma unroll
    for (int i = 0; i < 4; ++i) wrow[t + i * 256] = attn_w[h * 3072 + t + i * 256];
    __syncthreads();
    const int wave = t >> 6, lane = t & 63;
    const float bias = attn_b[h];
    for (int b = wave; b < 32; b += 4) {
        float s = 0.f;
#pragma unroll
        for (int j = 0; j < 16; ++j)
            s = fmaf(hidden[b * 1024 + lane + j * 64], wrow[lane + j * 64], s);
#pragma unroll
        for (int off = 1; off < 64; off <<= 1) s += __shfl_xor(s, off);
        if (lane == 0) hp[b * 1024 + h] = s + bias;
    }
}

// ---------------------------------------------------------------------------
// K1: 256x256-tile 8-phase bf16 MFMA GEMM (M=65536, N=1024, K=2048).
//
// Structure (m201 template, plain HIP):
//   - 512 threads = 8 waves (2M x 4N), per-wave C = 128x64 (8x4 16x16 frags)
//   - BK=64 per tile, split into 2 K-halves (kk) of 32; 4 phases/tile:
//       P0 (kk0, rows 0-63), P1 (kk0, rows 64-127), P2 (kk1, ...), P3
//   - LDS = 4-slot half-tile ring per operand (4x16KiB A + 4x16KiB B =128KiB)
//     slot(hs) = hs&3, hs = 2*tile + kk. Staging runs 3 half-steps ahead.
//   - counted s_waitcnt vmcnt(8) only at P1/P3 ends (never 0 in steady state)
//   - T2 swizzle: slot16B(row,k8) = row*4 + (k8 ^ ((row>>1)&3)); applied as
//     inverse-swizzled per-lane GLOBAL source (global_load_lds dest linear)
//     + same swizzle on ds_read side. All 64 lanes of a ds_read_b128 spread
//     across all 8 bank-groups -> conflict-free.
//   - T5: s_setprio(1) around each 16-MFMA cluster.
//   - XCD swizzle: nwg=1024 %8==0, same-XCD blocks share A panels.
// Epilogue: scores[m] += sum_n vw[n]*tanh(hp[b,n]+C[m,n]) partials (atomic).
// ---------------------------------------------------------------------------
__global__ __launch_bounds__(512, 2) void gemm8_score_kernel(
    const unsigned short* __restrict__ Abf,  // 65536 x 2048 bf16 bits
    const unsigned short* __restrict__ Bw,   // 1024 x 2048 bf16 bits
    const float* __restrict__ hp,            // 32 x 1024 fp32
    const float* __restrict__ vw,            // 1024 fp32
    float* __restrict__ scores)              // 65536 fp32 (pre-zeroed)
{
    __shared__ unsigned short lds[65536];    // 128 KiB: A [0,32768), B [32768,65536)

    const int bid = blockIdx.x;
    const int swz = (bid & 7) * 128 + (bid >> 3);   // bijective, 1024%8==0
    const int mt  = swz >> 2;                       // 0..255
    const int nt  = swz & 3;                        // 0..3
    const long tile_m = (long)mt * 256;
    const int  tile_n = nt * 256;

    const int tid  = threadIdx.x;
    const int w    = tid >> 6;
    const int lane = tid & 63;
    const int quad = lane >> 4;
    const int l15  = lane & 15;
    const int wm   = w >> 2;   // 0..1
    const int wn   = w & 3;    // 0..3

    // ---- staging: wave w, inst j covers 16B-slots (w*2+j)*64 + lane ----
    // slot s -> row = s>>2, q' = s&3 ; holds global (row, k8 = q'^((row>>1)&3))
    const int wrow0 = (w * 2 + 0) * 16 + (lane >> 2);
    const int wrow1 = (w * 2 + 1) * 16 + (lane >> 2);
    const int wk8   = (lane & 3) ^ ((lane >> 3) & 3);   // == q' ^ f(row), per lane
    const unsigned short* aS0 = Abf + (size_t)(tile_m + wrow0) * 2048 + wk8 * 8;
    const unsigned short* aS1 = Abf + (size_t)(tile_m + wrow1) * 2048 + wk8 * 8;
    const unsigned short* bS0 = Bw  + (size_t)(tile_n + wrow0) * 2048 + wk8 * 8;
    const unsigned short* bS1 = Bw  + (size_t)(tile_n + wrow1) * 2048 + wk8 * 8;
    const int ld0 = (w * 2 + 0) * 512;   // ushort offset within slot
    const int ld1 = (w * 2 + 1) * 512;

    // ---- reader: frag(row, k8=quad) at slot idx16 = row*4 + (quad^f(row)) ----
    // f(row) = (row>>1)&3 = (l15>>1)&3  (rows are base16*k + l15)
    const int qsw   = (quad ^ ((l15 >> 1) & 3)) * 8;
    const int aoffL = (wm * 128 + l15) * 32 + qsw;          // + mi*512 + slot*8192
    const int boffL = 32768 + (wn * 64 + l15) * 32 + qsw;   // + ni*512 + slot*8192

    f32x4 acc[8][4];
#pragma unroll
    for (int i = 0; i < 8; ++i)
#pragma unroll
        for (int j = 0; j < 4; ++j) acc[i][j] = (f32x4){0.f, 0.f, 0.f, 0.f};

#define G2L(srcp, dsti) __builtin_amdgcn_global_load_lds((const AS1 void*)(srcp), (AS3 void*)(&lds[(dsti)]), 16, 0, 0)
#define ISSA(hs) do { const int sb_ = ((hs) & 3) * 8192;             \
        G2L(aS0 + (size_t)(hs) * 32, sb_ + ld0);                     \
        G2L(aS1 + (size_t)(hs) * 32, sb_ + ld1); } while (0)
#define ISSB(hs) do { const int sb_ = 32768 + ((hs) & 3) * 8192;     \
        G2L(bS0 + (size_t)(hs) * 32, sb_ + ld0);                     \
        G2L(bS1 + (size_t)(hs) * 32, sb_ + ld1); } while (0)
#define BARX() do { asm volatile("" ::: "memory"); __builtin_amdgcn_s_barrier(); asm volatile("" ::: "memory"); } while (0)

    // prologue: stage half-steps 0,1,2 (12 loads/wave); certify hs0
    ISSA(0); ISSB(0); ISSA(1); ISSB(1); ISSA(2); ISSB(2);
    asm volatile("s_waitcnt vmcnt(8)" ::: "memory");
    BARX();

    bf16x8 af[4], bfr[4];
#pragma unroll 2
    for (int kt = 0; kt < 32; ++kt) {
        const int s0 = (2 * kt) & 3;       // kk0 slot (even)
        const int s1 = (2 * kt + 1) & 3;   // kk1 slot (odd)

        // ---- P0: kk0, wave-rows 0..63 ----
        if (kt < 31) ISSA(2 * kt + 3);     // writes odd slot != s0; anti-dep ok (prev P3 barrier)
#pragma unroll
        for (int i = 0; i < 4; ++i) af[i]  = *(const bf16x8*)&lds[s0 * 8192 + aoffL + i * 512];
#pragma unroll
        for (int i = 0; i < 4; ++i) bfr[i] = *(const bf16x8*)&lds[s0 * 8192 + boffL + i * 512];
        BARX();
        __builtin_amdgcn_s_setprio(1);
#pragma unroll
        for (int mi = 0; mi < 4; ++mi)
#pragma unroll
            for (int ni = 0; ni < 4; ++ni)
                acc[mi][ni] = __builtin_amdgcn_mfma_f32_16x16x32_bf16(af[mi], bfr[ni], acc[mi][ni], 0, 0, 0);
        __builtin_amdgcn_s_setprio(0);
        BARX();

        // ---- P1: kk0, wave-rows 64..127 ----
        if (kt < 31) ISSB(2 * kt + 3);
#pragma unroll
        for (int i = 0; i < 4; ++i) af[i] = *(const bf16x8*)&lds[s0 * 8192 + aoffL + (4 + i) * 512];
        BARX();
        __builtin_amdgcn_s_setprio(1);
#pragma unroll
        for (int mi = 0; mi < 4; ++mi)
#pragma unroll
            for (int ni = 0; ni < 4; ++ni)
                acc[4 + mi][ni] = __builtin_amdgcn_mfma_f32_16x16x32_bf16(af[mi], bfr[ni], acc[4 + mi][ni], 0, 0, 0);
        __builtin_amdgcn_s_setprio(0);
        // certify hs(2kt+1): loads issued after it = hs(2kt+2)[4] + hs(2kt+3)[4] = 8
        if (kt < 31) { asm volatile("s_waitcnt vmcnt(8)" ::: "memory"); }
        else         { asm volatile("s_waitcnt vmcnt(0)" ::: "memory"); }
        BARX();

        // ---- P2: kk1, wave-rows 0..63 ----
        if (kt < 30) ISSA(2 * kt + 4);     // writes even slot s0; reads of s0 done (P1-end barrier)
#pragma unroll
        for (int i = 0; i < 4; ++i) af[i]  = *(const bf16x8*)&lds[s1 * 8192 + aoffL + i * 512];
#pragma unroll
        for (int i = 0; i < 4; ++i) bfr[i] = *(const bf16x8*)&lds[s1 * 8192 + boffL + i * 512];
        BARX();
        __builtin_amdgcn_s_setprio(1);
#pragma unroll
        for (int mi = 0; mi < 4; ++mi)
#pragma unroll
            for (int ni = 0; ni < 4; ++ni)
                acc[mi][ni] = __builtin_amdgcn_mfma_f32_16x16x32_bf16(af[mi], bfr[ni], acc[mi][ni], 0, 0, 0);
        __builtin_amdgcn_s_setprio(0);
        BARX();

        // ---- P3: kk1, wave-rows 64..127 ----
        if (kt < 30) ISSB(2 * kt + 4);
#pragma unroll
        for (int i = 0; i < 4; ++i) af[i] = *(const bf16x8*)&lds[s1 * 8192 + aoffL + (4 + i) * 512];
        BARX();
        __builtin_amdgcn_s_setprio(1);
#pragma unroll
        for (int mi = 0; mi < 4; ++mi)
#pragma unroll
            for (int ni = 0; ni < 4; ++ni)
                acc[4 + mi][ni] = __builtin_amdgcn_mfma_f32_16x16x32_bf16(af[mi], bfr[ni], acc[4 + mi][ni], 0, 0, 0);
        __builtin_amdgcn_s_setprio(0);
        // certify hs(2kt+2): after it = hs(2kt+3)[4] + hs(2kt+4)[4 if kt<30]
        if (kt < 30) { asm volatile("s_waitcnt vmcnt(8)" ::: "memory"); }
        else         { asm volatile("s_waitcnt vmcnt(4)" ::: "memory"); }
        BARX();
    }
#undef G2L
#undef ISSA
#undef ISSB
#undef BARX

    // ---- epilogue: score partials ----
    const int bidx = (int)(tile_m >> 11);
    float vwv[4], hpv[4];
#pragma unroll
    for (int ni = 0; ni < 4; ++ni) {
        const int n = tile_n + wn * 64 + ni * 16 + l15;
        vwv[ni] = vw[n];
        hpv[ni] = hp[bidx * 1024 + n];
    }
#pragma unroll
    for (int mi = 0; mi < 8; ++mi) {
#pragma unroll
        for (int r = 0; r < 4; ++r) {
            float s = 0.f;
#pragma unroll
            for (int ni = 0; ni < 4; ++ni) {
                float x = hpv[ni] + acc[mi][ni][r];
                x = fminf(fmaxf(x, -12.f), 12.f);
                const float e  = __expf(x + x);
                const float th = (e - 1.f) * __builtin_amdgcn_rcpf(e + 1.f);
                s = fmaf(vwv[ni], th, s);
            }
            s += __shfl_xor(s, 1);
            s += __shfl_xor(s, 2);
            s += __shfl_xor(s, 4);
            s += __shfl_xor(s, 8);
            if (l15 == 0)
                atomicAdd(&scores[tile_m + wm * 128 + mi * 16 + quad * 4 + r], s);
        }
    }
}

// ---------------------------------------------------------------------------
// K1-fallback: in-kernel-cvt GEMM (used only if ws too small for encbf)
// ---------------------------------------------------------------------------
__global__ __launch_bounds__(256) void gemm_score_kernel(
    const float* __restrict__ A, const unsigned short* __restrict__ Bw,
    const float* __restrict__ hp, const float* __restrict__ vw,
    float* __restrict__ scores)
{
    __shared__ unsigned short As[128 * 32];
    __shared__ unsigned short Bs[128 * 32];
    const int id    = blockIdx.x;
    const int group = id >> 6;
    const int lid   = id & 63;
    const int mt    = group * 8 + (lid & 7);
    const int nt    = lid >> 3;
    const long tile_m = (long)mt * 128;
    const int  tile_n = nt * 128;
    const int t = threadIdx.x, wave = t >> 6, lane = t & 63;
    const int quad = lane >> 4, l15 = lane & 15;
    const int arow = t >> 2, akc = (t & 3) * 8;
    const float* aptr0 = A + (tile_m + arow) * 2048 + akc;
    const float* aptr1 = aptr0 + 64 * 2048;
    unsigned short* ad0 = &As[t * 8];
    unsigned short* ad1 = &As[(256 + t) * 8];
    const int bc0 = wave * 128 + lane;
    const int bc1 = bc0 + 64;
    const unsigned short* bptr0 = Bw + (tile_n + (bc0 >> 2)) * 2048 + (bc0 & 3) * 8;
    const unsigned short* bptr1 = Bw + (tile_n + (bc1 >> 2)) * 2048 + (bc1 & 3) * 8;
    unsigned short* bd0 = &Bs[(wave * 2 + 0) * 512];
    unsigned short* bd1 = &Bs[(wave * 2 + 1) * 512];
    const int wm = (wave >> 1) * 64, wn = (wave & 1) * 64;
    int aoff[4], boff[4];
#pragma unroll
    for (int i = 0; i < 4; ++i) {
        aoff[i] = (wm + i * 16 + l15) * 32 + quad * 8;
        boff[i] = (wn + i * 16 + l15) * 32 + quad * 8;
    }
    f32x4 acc[4][4];
#pragma unroll
    for (int i = 0; i < 4; ++i)
#pragma unroll
        for (int j = 0; j < 4; ++j) acc[i][j] = (f32x4){0.f, 0.f, 0.f, 0.f};
    f32x4 av0 = *(const f32x4*)aptr0;
    f32x4 av1 = *(const f32x4*)(aptr0 + 4);
    f32x4 av2 = *(const f32x4*)aptr1;
    f32x4 av3 = *(const f32x4*)(aptr1 + 4);
    for (int kt = 0; kt < 64; ++kt) {
        __syncthreads();
        __builtin_amdgcn_global_load_lds((const AS1 void*)bptr0, (AS3 void*)bd0, 16, 0, 0);
        __builtin_amdgcn_global_load_lds((const AS1 void*)bptr1, (AS3 void*)bd1, 16, 0, 0);
        bptr0 += 32; bptr1 += 32;
        uint4_ w0, w1;
        w0.x = pack2(av0.x, av0.y); w0.y = pack2(av0.z, av0.w);
        w0.z = pack2(av1.x, av1.y); w0.w = pack2(av1.z, av1.w);
        w1.x = pack2(av2.x, av2.y); w1.y = pack2(av2.z, av2.w);
        w1.z = pack2(av3.x, av3.y); w1.w = pack2(av3.z, av3.w);
        *(uint4_*)ad0 = w0;
        *(uint4_*)ad1 = w1;
        if (kt < 63) {
            aptr0 += 32; aptr1 += 32;
            av0 = *(const f32x4*)aptr0;
            av1 = *(const f32x4*)(aptr0 + 4);
            av2 = *(const f32x4*)aptr1;
            av3 = *(const f32x4*)(aptr1 + 4);
        }
        __syncthreads();
        bf16x8 af[4], bfr[4];
#pragma unroll
        for (int i = 0; i < 4; ++i) af[i]  = *(const bf16x8*)(&As[aoff[i]]);
#pragma unroll
        for (int i = 0; i < 4; ++i) bfr[i] = *(const bf16x8*)(&Bs[boff[i]]);
#pragma unroll
        for (int mi = 0; mi < 4; ++mi)
#pragma unroll
            for (int ni = 0; ni < 4; ++ni)
                acc[mi][ni] = __builtin_amdgcn_mfma_f32_16x16x32_bf16(
                    af[mi], bfr[ni], acc[mi][ni], 0, 0, 0);
    }
    const int bidx = mt >> 4;
    float vwv[4], hpv[4];
#pragma unroll
    for (int ni = 0; ni < 4; ++ni) {
        const int n = tile_n + wn + ni * 16 + l15;
        vwv[ni] = vw[n];
        hpv[ni] = hp[bidx * 1024 + n];
    }
#pragma unroll
    for (int mi = 0; mi < 4; ++mi) {
#pragma unroll
        for (int r = 0; r < 4; ++r) {
            float s = 0.f;
#pragma unroll
            for (int ni = 0; ni < 4; ++ni) {
                float x = hpv[ni] + acc[mi][ni][r];
                x = fminf(fmaxf(x, -12.f), 12.f);
                const float e  = __expf(x + x);
                const float th = (e - 1.f) * __builtin_amdgcn_rcpf(e + 1.f);
                s = fmaf(vwv[ni], th, s);
            }
            s += __shfl_xor(s, 1);
            s += __shfl_xor(s, 2);
            s += __shfl_xor(s, 4);
            s += __shfl_xor(s, 8);
            if (l15 == 0)
                atomicAdd(&scores[tile_m + wm + mi * 16 + quad * 4 + r], s);
        }
    }
}

// ---------------------------------------------------------------------------
// K2: softmax over S=2048, one block per batch
// ---------------------------------------------------------------------------
__global__ __launch_bounds__(256) void softmax_kernel(float* __restrict__ sc)
{
    __shared__ float red[8];
    const int b = blockIdx.x, t = threadIdx.x;
    const int wave = t >> 6, lane = t & 63;
    float* p = sc + b * 2048;
    float v[8];
#pragma unroll
    for (int i = 0; i < 8; ++i) v[i] = p[t + i * 256];
    float m = v[0];
#pragma unroll
    for (int i = 1; i < 8; ++i) m = fmaxf(m, v[i]);
#pragma unroll
    for (int off = 1; off < 64; off <<= 1) m = fmaxf(m, __shfl_xor(m, off));
    if (lane == 0) red[wave] = m;
    __syncthreads();
    m = fmaxf(fmaxf(red[0], red[1]), fmaxf(red[2], red[3]));
    float s = 0.f;
#pragma unroll
    for (int i = 0; i < 8; ++i) { v[i] = __expf(v[i] - m); s += v[i]; }
#pragma unroll
    for (int off = 1; off < 64; off <<= 1) s += __shfl_xor(s, off);
    if (lane == 0) red[4 + wave] = s;
    __syncthreads();
    s = red[4] + red[5] + red[6] + red[7];
    const float inv = 1.0f / s;
#pragma unroll
    for (int i = 0; i < 8; ++i) p[t + i * 256] = v[i] * inv;
}

// ---------------------------------------------------------------------------
// K3: context partials — block (b, sc) owns 128 s-rows, plain stores
// ---------------------------------------------------------------------------
__global__ __launch_bounds__(256) void context_part_kernel(
    const float* __restrict__ enc, const float* __restrict__ attn,
    float* __restrict__ part)
{
    const int b  = blockIdx.x >> 4;   // 32 batches
    const int sc = blockIdx.x & 15;   // 16 chunks of 128 rows
    const int t  = threadIdx.x;
    const float* ep = enc + ((size_t)(b * 2048 + sc * 128)) * 2048 + t * 8;
    const float* ap = attn + b * 2048 + sc * 128;
    f32x4 a0 = (f32x4){0.f, 0.f, 0.f, 0.f};
    f32x4 a1 = (f32x4){0.f, 0.f, 0.f, 0.f};
#pragma unroll 4
    for (int s = 0; s < 128; ++s) {
        const float w = ap[s];
        f32x4 v0 = *(const f32x4*)ep;
        f32x4 v1 = *(const f32x4*)(ep + 4);
        a0 += w * v0;
        a1 += w * v1;
        ep += 2048;
    }
    float* pp = part + ((size_t)(b * 16 + sc)) * 2048 + t * 8;
    *(f32x4*)pp = a0;
    *(f32x4*)(pp + 4) = a1;
}

__global__ __launch_bounds__(256) void context_reduce_kernel(
    const float* __restrict__ part, float* __restrict__ ctx)
{
    const int idx = blockIdx.x * 256 + threadIdx.x;  // 65536 = b*2048 + e
    const int b = idx >> 11, e = idx & 2047;
    const float* pp = part + ((size_t)b * 16) * 2048 + e;
    float s = 0.f;
#pragma unroll
    for (int i = 0; i < 16; ++i) s += pp[i * 2048];
    ctx[idx] = s;
}

// ---------------------------------------------------------------------------
// K3-fallback: atomic context (used only if ws can't hold partials)
// ---------------------------------------------------------------------------
__global__ __launch_bounds__(256) void context_kernel(
    const float* __restrict__ enc, const float* __restrict__ attn,
    float* __restrict__ ctx)
{
    const int b  = blockIdx.x >> 5;
    const int sc = blockIdx.x & 31;
    const int t  = threadIdx.x;
    const float* ep = enc + ((long)(b * 2048 + sc * 64)) * 2048 + t * 8;
    const float* ap = attn + b * 2048 + sc * 64;
    f32x4 a0 = (f32x4){0.f, 0.f, 0.f, 0.f};
    f32x4 a1 = (f32x4){0.f, 0.f, 0.f, 0.f};
#pragma unroll 4
    for (int s = 0; s < 64; ++s) {
        const float w = ap[s];
        f32x4 v0 = *(const f32x4*)ep;
        f32x4 v1 = *(const f32x4*)(ep + 4);
        a0 += w * v0;
        a1 += w * v1;
        ep += 2048;
    }
    float* cp = ctx + b * 2048 + t * 8;
    atomicAdd(&cp[0], a0.x); atomicAdd(&cp[1], a0.y);
    atomicAdd(&cp[2], a0.z); atomicAdd(&cp[3], a0.w);
    atomicAdd(&cp[4], a1.x); atomicAdd(&cp[5], a1.y);
    atomicAdd(&cp[6], a1.z); atomicAdd(&cp[7], a1.w);
}

// ---------------------------------------------------------------------------
extern "C" void kernel_launch(void* const* d_in, const int* in_sizes, int n_in,
                              void* d_out, int out_size, void* d_ws, size_t ws_size,
                              hipStream_t stream)
{
    const float* hidden = (const float*)d_in[0];   // 32 x 1024
    const float* enc    = (const float*)d_in[1];   // 32 x 2048 x 2048
    const float* attn_w = (const float*)d_in[2];   // 1024 x 3072
    const float* attn_b = (const float*)d_in[3];   // 1024
    const float* vw     = (const float*)d_in[4];   // 1024
    float* out = (float*)d_out;

    // ws layout: [Bw 4MiB][hp 128KiB][part 4MiB][encbf 256MiB]
    const size_t off_Bw   = 0;
    const size_t off_hp   = (size_t)1024 * 2048 * 2;          // 4 MiB
    const size_t off_part = off_hp + (size_t)32 * 1024 * 4;   // +128 KiB
    const size_t off_enc  = off_part + (size_t)512 * 2048 * 4;// +4 MiB
    const size_t need_part = off_enc;
    const size_t need_full = off_enc + (size_t)65536 * 2048 * 2;

    unsigned short* Bw   = (unsigned short*)((char*)d_ws + off_Bw);
    float*          hp   = (float*)((char*)d_ws + off_hp);
    float*          part = (float*)((char*)d_ws + off_part);
    unsigned short* encbf= (unsigned short*)((char*)d_ws + off_enc);

    float* ctx  = out;            // 32 x 2048
    float* attn = out + 65536;    // 32 x 2048 (scores -> weights in place)

    hipMemsetAsync(d_out, 0, (size_t)out_size * 4, stream);
    convwe_kernel <<<1024, 256, 0, stream>>>(attn_w, Bw);
    hidproj_kernel<<<1024, 256, 0, stream>>>(hidden, attn_w, attn_b, hp);

    if (ws_size >= need_full) {
        convenc_kernel<<<2048, 256, 0, stream>>>(enc, encbf);
        gemm8_score_kernel<<<1024, 512, 0, stream>>>(encbf, Bw, hp, vw, attn);
    } else {
        gemm_score_kernel<<<4096, 256, 0, stream>>>(enc, Bw, hp, vw, attn);
    }

    softmax_kernel<<<32, 256, 0, stream>>>(attn);

    if (ws_size >= need_part) {
        context_part_kernel  <<<512, 256, 0, stream>>>(enc, attn, part);
        context_reduce_kernel<<<256, 256, 0, stream>>>(part, ctx);
    } else {
        context_kernel<<<1024, 256, 0, stream>>>(enc, attn, ctx);
    }
}